// Round 1
// baseline (205.901 us; speedup 1.0000x reference)
//
#include <hip/hip_runtime.h>
#include <hip/hip_bf16.h>
#include <stdint.h>

#define HID 256
#define NTOK 8192

typedef unsigned short u16;
typedef unsigned int u32;

typedef __bf16 bf16x8 __attribute__((ext_vector_type(8)));
typedef float f32x4 __attribute__((ext_vector_type(4)));

// fp32 -> bf16 round-to-nearest-even
__device__ __forceinline__ u16 f2bf(float f) {
  u32 u = __float_as_uint(f);
  u32 r = (u + 0x7FFFu + ((u >> 16) & 1u)) >> 16;
  return (u16)r;
}

// XOR swizzle: 16B slots within a row, slot ^= (row&7). ld = elems per row (64 or 256).
__device__ __forceinline__ int swz(int row, int col, int ld) {
  return row * ld + ((((col >> 3) ^ (row & 7)) << 3) | (col & 7));
}

// ---------------------------------------------------------------------------
// Projection: out = bf16(X @ W^T + b). sel 0,1 -> row-major oq/ok[8192][256];
// sel 2 -> transposed ovt[256][8192].
// ---------------------------------------------------------------------------
__global__ __launch_bounds__(256, 2) void proj_kernel(
    const float* __restrict__ Xq, const float* __restrict__ Xk, const float* __restrict__ Xv,
    const float* __restrict__ Wq, const float* __restrict__ Bq,
    const float* __restrict__ Wk, const float* __restrict__ Bk,
    const float* __restrict__ Wv, const float* __restrict__ Bv,
    u16* __restrict__ oq, u16* __restrict__ ok, u16* __restrict__ ovt)
{
  __shared__ __attribute__((aligned(16))) u16 Xs[64 * 64];    // 8 KB, swizzled ld=64
  __shared__ __attribute__((aligned(16))) u16 Ws[256 * 64];   // 32 KB, swizzled ld=64
  __shared__ __attribute__((aligned(16))) u16 Ts[64 * 256];   // 32 KB, linear (epilogue)

  const int tid = threadIdx.x;
  const int bid = blockIdx.x;
  const int sel = bid >> 7;          // 0:q 1:k 2:v
  const int m0 = (bid & 127) << 6;   // 64 rows per block

  const float* X = sel == 0 ? Xq : (sel == 1 ? Xk : Xv);
  const float* W = sel == 0 ? Wq : (sel == 1 ? Wk : Wv);
  const float* B = sel == 0 ? Bq : (sel == 1 ? Bk : Bv);

  const int wid = tid >> 6;
  const int lane = tid & 63;
  const int ln = lane & 15;
  const int hi = lane >> 4;
  const int trow = tid >> 2;   // 0..63
  const int tq = tid & 3;      // quarter of 64-col chunk

  f32x4 acc[4][4];
#pragma unroll
  for (int i = 0; i < 4; ++i)
#pragma unroll
    for (int j = 0; j < 4; ++j) acc[i][j] = (f32x4)0.f;

  for (int kc = 0; kc < 4; ++kc) {
    const int k0 = kc << 6;
    // stage X chunk [64][64] fp32->bf16
    {
      const float* g = X + (size_t)(m0 + trow) * HID + k0 + tq * 16;
      u16 tmp[16];
#pragma unroll
      for (int e = 0; e < 16; e += 4) {
        float4 v = *reinterpret_cast<const float4*>(g + e);
        tmp[e] = f2bf(v.x); tmp[e + 1] = f2bf(v.y);
        tmp[e + 2] = f2bf(v.z); tmp[e + 3] = f2bf(v.w);
      }
      *reinterpret_cast<uint4*>(&Xs[swz(trow, tq * 16, 64)]) = *reinterpret_cast<uint4*>(&tmp[0]);
      *reinterpret_cast<uint4*>(&Xs[swz(trow, tq * 16 + 8, 64)]) = *reinterpret_cast<uint4*>(&tmp[8]);
    }
    // stage W chunk [256][64] fp32->bf16
#pragma unroll
    for (int p = 0; p < 4; ++p) {
      int n = p * 64 + trow;
      const float* g = W + (size_t)n * HID + k0 + tq * 16;
      u16 tmp[16];
#pragma unroll
      for (int e = 0; e < 16; e += 4) {
        float4 v = *reinterpret_cast<const float4*>(g + e);
        tmp[e] = f2bf(v.x); tmp[e + 1] = f2bf(v.y);
        tmp[e + 2] = f2bf(v.z); tmp[e + 3] = f2bf(v.w);
      }
      *reinterpret_cast<uint4*>(&Ws[swz(n, tq * 16, 64)]) = *reinterpret_cast<uint4*>(&tmp[0]);
      *reinterpret_cast<uint4*>(&Ws[swz(n, tq * 16 + 8, 64)]) = *reinterpret_cast<uint4*>(&tmp[8]);
    }
    __syncthreads();
#pragma unroll
    for (int kk = 0; kk < 64; kk += 32) {
      bf16x8 a[4], b[4];
#pragma unroll
      for (int i = 0; i < 4; ++i)
        a[i] = *reinterpret_cast<bf16x8*>(&Xs[swz(i * 16 + ln, kk + hi * 8, 64)]);
#pragma unroll
      for (int j = 0; j < 4; ++j)
        b[j] = *reinterpret_cast<bf16x8*>(&Ws[swz(wid * 64 + j * 16 + ln, kk + hi * 8, 64)]);
#pragma unroll
      for (int i = 0; i < 4; ++i)
#pragma unroll
        for (int j = 0; j < 4; ++j)
          acc[i][j] = __builtin_amdgcn_mfma_f32_16x16x32_bf16(a[i], b[j], acc[i][j], 0, 0, 0);
    }
    __syncthreads();
  }

  // epilogue: bias + bf16 -> Ts (linear [64][256])
#pragma unroll
  for (int j = 0; j < 4; ++j) {
    int col = wid * 64 + j * 16 + ln;
    float bv = B[col];
#pragma unroll
    for (int i = 0; i < 4; ++i)
#pragma unroll
      for (int r = 0; r < 4; ++r) {
        int row = i * 16 + hi * 4 + r;
        Ts[row * HID + col] = f2bf(acc[i][j][r] + bv);
      }
  }
  __syncthreads();

  if (sel < 2) {
    u16* o = sel == 0 ? oq : ok;
#pragma unroll
    for (int i = 0; i < 8; ++i) {
      int slot = i * 256 + tid;            // 2048 slots of 8 elems
      int row = slot >> 5, s = slot & 31;
      uint4 v = *reinterpret_cast<uint4*>(&Ts[row * HID + s * 8]);
      *reinterpret_cast<uint4*>(&o[(size_t)(m0 + row) * HID + s * 8]) = v;
    }
  } else {
    // transpose: ovt[n][m0..m0+64)
#pragma unroll
    for (int p = 0; p < 4; ++p) {
      int n = p * 64 + trow;
      int mseg = tq * 16;
      u16 tmp[16];
#pragma unroll
      for (int j2 = 0; j2 < 16; ++j2)
        tmp[j2] = Ts[(mseg + j2) * HID + n];
      *reinterpret_cast<uint4*>(&ovt[(size_t)n * NTOK + m0 + mseg]) = *reinterpret_cast<uint4*>(&tmp[0]);
      *reinterpret_cast<uint4*>(&ovt[(size_t)n * NTOK + m0 + mseg + 8]) = *reinterpret_cast<uint4*>(&tmp[8]);
    }
  }
}

// ---------------------------------------------------------------------------
// Fused sigmoid attention: O += sigmoid(Q K^T) V  for one (Q-tile, KV-slice)
// ---------------------------------------------------------------------------
#define QB 128
#define KVB 64
#define NSLICE 4
#define SLICE_LEN (NTOK / NSLICE)   // 2048
#define NCH (SLICE_LEN / KVB)       // 32

__global__ __launch_bounds__(512, 2) void attn_kernel(
    const u16* __restrict__ qw, const u16* __restrict__ kw,
    const u16* __restrict__ vtw, float* __restrict__ out)
{
  __shared__ __attribute__((aligned(16))) u16 Qs[QB * HID];   // 64 KB, ld=256 swz
  __shared__ __attribute__((aligned(16))) u16 Ks[KVB * HID];  // 32 KB, ld=256 swz
  __shared__ __attribute__((aligned(16))) u16 Vs[HID * KVB];  // 32 KB, ld=64 swz (row=d, col=j)
  __shared__ __attribute__((aligned(16))) u16 Ps[QB * KVB];   // 16 KB, ld=64 swz

  const int tid = threadIdx.x;
  const int bid = blockIdx.x;
  const int qt = bid >> 2, slice = bid & 3;
  const int m0 = qt * QB;
  const int kvbase = slice * SLICE_LEN;

  const int wid = tid >> 6, lane = tid & 63;
  const int ln = lane & 15, hi = lane >> 4;
  const int wr = wid >> 1, wc = wid & 1;

  // stage helpers: global_load_lds 16B, linear LDS dest, inverse-swizzled source
  auto stageQ = [&]() {
    int r_in = lane >> 5, s = lane & 31;
    for (int i = wid; i < 64; i += 8) {
      int r = i * 2 + r_in;
      const u16* g = qw + (size_t)(m0 + r) * HID + ((s ^ (r & 7)) << 3);
      __builtin_amdgcn_global_load_lds((const __attribute__((address_space(1))) u32*)g,
                                       (__attribute__((address_space(3))) u32*)(&Qs[i * 512]),
                                       16, 0, 0);
    }
  };
  auto stageK = [&](int ch) {
    int j0 = kvbase + ch * KVB;
    int r_in = lane >> 5, s = lane & 31;
    for (int i = wid; i < 32; i += 8) {
      int r = i * 2 + r_in;
      const u16* g = kw + (size_t)(j0 + r) * HID + ((s ^ (r & 7)) << 3);
      __builtin_amdgcn_global_load_lds((const __attribute__((address_space(1))) u32*)g,
                                       (__attribute__((address_space(3))) u32*)(&Ks[i * 512]),
                                       16, 0, 0);
    }
  };
  auto stageV = [&](int ch) {
    int j0 = kvbase + ch * KVB;
    int r_in = lane >> 3, s = lane & 7;
    for (int i = wid; i < 32; i += 8) {
      int d = i * 8 + r_in;
      const u16* g = vtw + (size_t)d * NTOK + j0 + ((s ^ (d & 7)) << 3);
      __builtin_amdgcn_global_load_lds((const __attribute__((address_space(1))) u32*)g,
                                       (__attribute__((address_space(3))) u32*)(&Vs[i * 512]),
                                       16, 0, 0);
    }
  };

  stageQ();
  stageK(0);
  stageV(0);

  f32x4 oacc[2][8];
#pragma unroll
  for (int i = 0; i < 2; ++i)
#pragma unroll
    for (int cb = 0; cb < 8; ++cb) oacc[i][cb] = (f32x4)0.f;

  __syncthreads();   // drains staging vmcnt

  for (int c = 0; c < NCH; ++c) {
    // ---- S = Q K^T  (per wave: rows wr*32+[0,32), cols wc*32+[0,32))
    f32x4 sacc[2][2];
#pragma unroll
    for (int i = 0; i < 2; ++i)
#pragma unroll
      for (int j = 0; j < 2; ++j) sacc[i][j] = (f32x4)0.f;

#pragma unroll
    for (int kk = 0; kk < 8; ++kk) {
      bf16x8 aq[2], bk[2];
#pragma unroll
      for (int i = 0; i < 2; ++i) {
        int qr = wr * 32 + i * 16 + ln;
        aq[i] = *reinterpret_cast<bf16x8*>(&Qs[qr * HID + ((((kk * 4 + hi) ^ (qr & 7))) << 3)]);
      }
#pragma unroll
      for (int j = 0; j < 2; ++j) {
        int kr = wc * 32 + j * 16 + ln;
        bk[j] = *reinterpret_cast<bf16x8*>(&Ks[kr * HID + ((((kk * 4 + hi) ^ (kr & 7))) << 3)]);
      }
#pragma unroll
      for (int i = 0; i < 2; ++i)
#pragma unroll
        for (int j = 0; j < 2; ++j)
          sacc[i][j] = __builtin_amdgcn_mfma_f32_16x16x32_bf16(aq[i], bk[j], sacc[i][j], 0, 0, 0);
    }

    // ---- sigmoid -> P (bf16, swizzled)
#pragma unroll
    for (int i = 0; i < 2; ++i)
#pragma unroll
      for (int j = 0; j < 2; ++j)
#pragma unroll
        for (int r = 0; r < 4; ++r) {
          float s = sacc[i][j][r];
          float p = __builtin_amdgcn_rcpf(1.0f + __expf(-s));
          int prow = wr * 32 + i * 16 + hi * 4 + r;
          int pcol = wc * 32 + j * 16 + ln;
          Ps[swz(prow, pcol, KVB)] = f2bf(p);
        }

    __syncthreads();            // P visible; Ks free
    if (c + 1 < NCH) stageK(c + 1);   // overlaps PV; lands at next barrier

    // ---- O += P V  (per wave: rows wr*32+[0,32), cols wc*128+[0,128))
#pragma unroll
    for (int ks = 0; ks < 2; ++ks) {
      bf16x8 ap[2];
#pragma unroll
      for (int i = 0; i < 2; ++i) {
        int pr = wr * 32 + i * 16 + ln;
        ap[i] = *reinterpret_cast<bf16x8*>(&Ps[pr * KVB + ((((ks * 4 + hi) ^ (pr & 7))) << 3)]);
      }
#pragma unroll
      for (int cb = 0; cb < 8; ++cb) {
        int vr = wc * 128 + cb * 16 + ln;
        bf16x8 bv = *reinterpret_cast<bf16x8*>(&Vs[vr * KVB + ((((ks * 4 + hi) ^ (vr & 7))) << 3)]);
#pragma unroll
        for (int i = 0; i < 2; ++i)
          oacc[i][cb] = __builtin_amdgcn_mfma_f32_16x16x32_bf16(ap[i], bv, oacc[i][cb], 0, 0, 0);
      }
    }

    __syncthreads();            // Vs free (PV done); K(c+1) landed
    if (c + 1 < NCH) stageV(c + 1);   // overlaps next S; lands at next barrier
  }

  // ---- epilogue: accumulate slices into out
#pragma unroll
  for (int i = 0; i < 2; ++i)
#pragma unroll
    for (int cb = 0; cb < 8; ++cb)
#pragma unroll
      for (int r = 0; r < 4; ++r) {
        int row = m0 + wr * 32 + i * 16 + hi * 4 + r;
        int col = wc * 128 + cb * 16 + ln;
        atomicAdd(&out[(size_t)row * HID + col], oacc[i][cb][r]);
      }
}

extern "C" void kernel_launch(void* const* d_in, const int* in_sizes, int n_in,
                              void* d_out, int out_size, void* d_ws, size_t ws_size,
                              hipStream_t stream) {
  const float* query = (const float*)d_in[0];
  const float* key_  = (const float*)d_in[1];
  const float* value = (const float*)d_in[2];
  const float* Wq = (const float*)d_in[3];
  const float* bq = (const float*)d_in[4];
  const float* Wk = (const float*)d_in[5];
  const float* bk = (const float*)d_in[6];
  const float* Wv = (const float*)d_in[7];
  const float* bv = (const float*)d_in[8];
  float* out = (float*)d_out;

  u16* qws  = (u16*)d_ws;                 // [8192][256] bf16
  u16* kws  = qws + (size_t)NTOK * HID;   // [8192][256] bf16
  u16* vtws = kws + (size_t)NTOK * HID;   // [256][8192] bf16 (V transposed)

  hipMemsetAsync(d_out, 0, (size_t)NTOK * HID * sizeof(float), stream);
  proj_kernel<<<384, 256, 0, stream>>>(query, key_, value, Wq, bq, Wk, bk, Wv, bv,
                                       qws, kws, vtws);
  attn_kernel<<<256, 512, 0, stream>>>(qws, kws, vtws, out);
}

// Round 3
// 184.740 us; speedup vs baseline: 1.1145x; 1.1145x over previous
//
#include <hip/hip_runtime.h>
#include <hip/hip_bf16.h>
#include <stdint.h>

#define HID 256
#define NTOK 8192
#define NS 8
#define SLICE (NTOK / NS)        // 1024 tokens per slice
#define CHUNK 32
#define NCH (SLICE / CHUNK)      // 32 chunks

typedef unsigned short u16;
typedef unsigned int u32;
typedef __bf16 bf16x8 __attribute__((ext_vector_type(8)));
typedef float f32x16 __attribute__((ext_vector_type(16)));
typedef __fp16 h16x2 __attribute__((ext_vector_type(2)));

// D-layout row index for 32x32 MFMA: row = (r&3) + 8*(r>>2) + 4*h
#define TAU(r, h) (((r) & 3) + 8 * ((r) >> 2) + 4 * (h))

__device__ __forceinline__ u16 f2bf(float f) {
  u32 u = __float_as_uint(f);
  return (u16)((u + 0x7FFFu + ((u >> 16) & 1u)) >> 16);
}

__device__ __forceinline__ u32 cvtpk_bf16(float a, float b) {
  u32 r;
  asm("v_cvt_pk_bf16_f32 %0, %1, %2" : "=v"(r) : "v"(a), "v"(b));
  return r;
}

// ---------------------------------------------------------------------------
// W fp32 -> bf16 (3 x 256x256)
// ---------------------------------------------------------------------------
__global__ void wcvt_kernel(const float* __restrict__ Wq, const float* __restrict__ Wk,
                            const float* __restrict__ Wv, u16* __restrict__ out) {
  int idx = blockIdx.x * 256 + threadIdx.x;   // 49152 threads, 4 elems each
  int mat = idx >> 14;
  int off = (idx & 16383) << 2;
  const float* src = mat == 0 ? Wq : (mat == 1 ? Wk : Wv);
  float4 v = *reinterpret_cast<const float4*>(src + off);
  ushort4 o;
  o.x = f2bf(v.x); o.y = f2bf(v.y); o.z = f2bf(v.z); o.w = f2bf(v.w);
  *reinterpret_cast<ushort4*>(out + mat * 65536 + off) = o;
}

// ---------------------------------------------------------------------------
// Projection: out = bf16(X @ W^T + b); q,k row-major [8192][256], v -> [256][8192]
// block: 256 thr (4 waves), 128 rows; grid 192 = 3 * 64
// ---------------------------------------------------------------------------
__global__ __launch_bounds__(256, 2) void proj_kernel(
    const float* __restrict__ Xq, const float* __restrict__ Xk, const float* __restrict__ Xv,
    const u16* __restrict__ wcvt,
    const float* __restrict__ Bq, const float* __restrict__ Bk, const float* __restrict__ Bv,
    u16* __restrict__ oq, u16* __restrict__ ok, u16* __restrict__ ovt)
{
  __shared__ __attribute__((aligned(16))) unsigned char smem[32768 + 4 * 4352];
  u16* wbuf0 = (u16*)smem;
  u16* wbuf1 = (u16*)(smem + 16384);
  float* scratch = (float*)(smem + 32768 + (threadIdx.x >> 6) * 4352);

  const int tid = threadIdx.x, bid = blockIdx.x;
  const int sel = bid >> 6;             // 0:q 1:k 2:v
  const int m0 = (bid & 63) << 7;       // 128 rows/block
  const int wid = tid >> 6, l = tid & 63;
  const int l31 = l & 31, lh = l >> 5;

  const float* X = sel == 0 ? Xq : (sel == 1 ? Xk : Xv);
  const u16* W = wcvt + sel * 65536;
  const float* B = sel == 0 ? Bq : (sel == 1 ? Bk : Bv);
  const int mrow = m0 + wid * 32 + l31;

  f32x16 acc[8];
#pragma unroll
  for (int nt = 0; nt < 8; ++nt) acc[nt] = (f32x16)0.f;

  auto stageW = [&](int kc, u16* buf) {
    // W chunk [4 hid-octet][256 n] of 16B units, linear LDS dest
#pragma unroll
    for (int ii = 0; ii < 4; ++ii) {
      int u = (wid * 4 + ii) * 64 + l;
      int ol = u >> 8, n = u & 255;
      const u16* g = W + n * HID + kc * 32 + ol * 8;
      __builtin_amdgcn_global_load_lds((const __attribute__((address_space(1))) u32*)g,
                                       (__attribute__((address_space(3))) u32*)(buf + (size_t)u * 8),
                                       16, 0, 0);
    }
  };

  stageW(0, wbuf0);
  __syncthreads();
  for (int kc = 0; kc < 8; ++kc) {
    u16* cur = (kc & 1) ? wbuf1 : wbuf0;
    if (kc < 7) stageW(kc + 1, (kc & 1) ? wbuf0 : wbuf1);
#pragma unroll
    for (int k2 = 0; k2 < 2; ++k2) {
      int ks = kc * 2 + k2;
      float4 a0 = *reinterpret_cast<const float4*>(X + (size_t)mrow * HID + ks * 16 + lh * 8);
      float4 a1 = *reinterpret_cast<const float4*>(X + (size_t)mrow * HID + ks * 16 + lh * 8 + 4);
      union { u16 u[8]; bf16x8 v; } au;
      au.u[0] = f2bf(a0.x); au.u[1] = f2bf(a0.y); au.u[2] = f2bf(a0.z); au.u[3] = f2bf(a0.w);
      au.u[4] = f2bf(a1.x); au.u[5] = f2bf(a1.y); au.u[6] = f2bf(a1.z); au.u[7] = f2bf(a1.w);
#pragma unroll
      for (int nt = 0; nt < 8; ++nt) {
        int unit = (k2 * 2 + lh) * 256 + nt * 32 + l31;
        bf16x8 b = *reinterpret_cast<bf16x8*>(cur + (size_t)unit * 8);
        acc[nt] = __builtin_amdgcn_mfma_f32_32x32x16_bf16(au.v, b, acc[nt], 0, 0, 0);
      }
    }
    __syncthreads();
  }

  // epilogue: bias (col = nt*32+l31 is lane-fixed), transpose via stride-33 scratch
#pragma unroll
  for (int nt = 0; nt < 8; ++nt) {
    float bv = B[nt * 32 + l31];
#pragma unroll
    for (int r = 0; r < 16; ++r)
      scratch[TAU(r, lh) * 33 + l31] = acc[nt][r] + bv;   // [m_local][n_local]
    if (sel < 2) {
      u16* o = sel == 0 ? oq : ok;
      u16 tmp[16];
#pragma unroll
      for (int c = 0; c < 16; ++c) tmp[c] = f2bf(scratch[l31 * 33 + lh * 16 + c]);
      u16* dst = o + (size_t)(m0 + wid * 32 + l31) * HID + nt * 32 + lh * 16;
      *reinterpret_cast<uint4*>(dst) = *reinterpret_cast<uint4*>(&tmp[0]);
      *reinterpret_cast<uint4*>(dst + 8) = *reinterpret_cast<uint4*>(&tmp[8]);
    } else {
      u16 tmp[16];
#pragma unroll
      for (int c = 0; c < 16; ++c) tmp[c] = f2bf(scratch[(lh * 16 + c) * 33 + l31]);
      u16* dst = ovt + (size_t)(nt * 32 + l31) * NTOK + m0 + wid * 32 + lh * 16;
      *reinterpret_cast<uint4*>(dst) = *reinterpret_cast<uint4*>(&tmp[0]);
      *reinterpret_cast<uint4*>(dst + 8) = *reinterpret_cast<uint4*>(&tmp[8]);
    }
  }
}

// ---------------------------------------------------------------------------
// Fused sigmoid attention, swapped operands, P in registers.
// block: 512 thr (8 waves, 32 q-rows each -> 256 q); grid 256 = 32 qt * 8 slices
// slice = bid & 7  (pins slice to XCD -> K/V slice L2-resident)
// ---------------------------------------------------------------------------
__global__ __launch_bounds__(512, 2) void attn_kernel(
    const u16* __restrict__ qw, const u16* __restrict__ kw,
    const u16* __restrict__ vtw, u16* __restrict__ partial)
{
  __shared__ __attribute__((aligned(16))) unsigned char smem[65536];
  u16* kb0 = (u16*)smem;            u16* kb1 = (u16*)(smem + 16384);
  u16* vb0 = (u16*)(smem + 32768);  u16* vb1 = (u16*)(smem + 49152);

  const int tid = threadIdx.x, bid = blockIdx.x;
  const int slice = bid & 7, qt = bid >> 3;
  const int q0 = qt * 256;
  const int tokbase = slice * SLICE;
  const int wq = tid >> 6, l = tid & 63;
  const int l31 = l & 31, lh = l >> 5;
  const int qrow = q0 + wq * 32 + l31;

  // Q B-fragments in registers: qB[ks] = Q[qrow][ks*16 + lh*8 + 0..7]
  bf16x8 qB[16];
#pragma unroll
  for (int ks = 0; ks < 16; ++ks)
    qB[ks] = *reinterpret_cast<const bf16x8*>(qw + (size_t)qrow * HID + ks * 16 + lh * 8);

  auto stageK = [&](int c, u16* buf) {   // [32 hid-octet][32 tok] 16B units
    int tok0 = tokbase + c * CHUNK;
#pragma unroll
    for (int ii = 0; ii < 2; ++ii) {
      int u = (wq * 2 + ii) * 64 + l;
      int o = u >> 5, t = u & 31;
      const u16* g = kw + (size_t)(tok0 + t) * HID + o * 8;
      __builtin_amdgcn_global_load_lds((const __attribute__((address_space(1))) u32*)g,
                                       (__attribute__((address_space(3))) u32*)(buf + (size_t)u * 8),
                                       16, 0, 0);
    }
  };
  auto stageV = [&](int c, u16* buf) {   // [4 tok-octet][256 d] 16B units
    int tok0 = tokbase + c * CHUNK;
#pragma unroll
    for (int ii = 0; ii < 2; ++ii) {
      int u = (wq * 2 + ii) * 64 + l;
      int j = u >> 8, d = u & 255;
      const u16* g = vtw + (size_t)d * NTOK + tok0 + j * 8;
      __builtin_amdgcn_global_load_lds((const __attribute__((address_space(1))) u32*)g,
                                       (__attribute__((address_space(3))) u32*)(buf + (size_t)u * 8),
                                       16, 0, 0);
    }
  };

  f32x16 oacc[8];
#pragma unroll
  for (int dt = 0; dt < 8; ++dt) oacc[dt] = (f32x16)0.f;

  stageK(0, kb0);
  stageV(0, vb0);
  __syncthreads();

  for (int c = 0; c < NCH; ++c) {
    u16* kc_ = (c & 1) ? kb1 : kb0;
    u16* vc_ = (c & 1) ? vb1 : vb0;
    if (c + 1 < NCH) {
      stageK(c + 1, (c & 1) ? kb0 : kb1);
      stageV(c + 1, (c & 1) ? vb0 : vb1);
    }

    // S^T = K * Q^T   (rows = 32 tokens, cols = 32 q)
    f32x16 sacc = (f32x16)0.f;
#pragma unroll
    for (int ks = 0; ks < 16; ++ks) {
      bf16x8 kf = *reinterpret_cast<bf16x8*>(kc_ + (size_t)((ks * 2 + lh) * 32 + l31) * 8);
      sacc = __builtin_amdgcn_mfma_f32_32x32x16_bf16(kf, qB[ks], sacc, 0, 0, 0);
    }

    // sigmoid (elementwise, no reduction)
    float p[16];
#pragma unroll
    for (int r = 0; r < 16; ++r) {
      float e = __expf(-sacc[r]);
      p[r] = __builtin_amdgcn_rcpf(1.0f + e);
    }

    // pack P^T into PV B-fragments: 8 cvt_pk + 4 permlane32_swap
    u32 w0[4], w1[4];
    {
      u32 x0 = cvtpk_bf16(p[0], p[1]),  y0 = cvtpk_bf16(p[4], p[5]);
      asm volatile("v_permlane32_swap_b32 %0, %1" : "+v"(x0), "+v"(y0));
      u32 x1 = cvtpk_bf16(p[2], p[3]),  y1 = cvtpk_bf16(p[6], p[7]);
      asm volatile("v_permlane32_swap_b32 %0, %1" : "+v"(x1), "+v"(y1));
      w0[0] = x0; w0[1] = x1; w0[2] = y0; w0[3] = y1;
      u32 x2 = cvtpk_bf16(p[8], p[9]),  y2 = cvtpk_bf16(p[12], p[13]);
      asm volatile("v_permlane32_swap_b32 %0, %1" : "+v"(x2), "+v"(y2));
      u32 x3 = cvtpk_bf16(p[10], p[11]), y3 = cvtpk_bf16(p[14], p[15]);
      asm volatile("v_permlane32_swap_b32 %0, %1" : "+v"(x3), "+v"(y3));
      w1[0] = x2; w1[1] = x3; w1[2] = y2; w1[3] = y3;
    }

    // O^T += V^T * P^T   (rows = d, cols = q)
#pragma unroll
    for (int kp = 0; kp < 2; ++kp) {
      union { u32 u[4]; bf16x8 v; } pb;
      pb.u[0] = kp ? w1[0] : w0[0]; pb.u[1] = kp ? w1[1] : w0[1];
      pb.u[2] = kp ? w1[2] : w0[2]; pb.u[3] = kp ? w1[3] : w0[3];
#pragma unroll
      for (int dt = 0; dt < 8; ++dt) {
        bf16x8 vf = *reinterpret_cast<bf16x8*>(vc_ + (size_t)((kp * 2 + lh) * 256 + dt * 32 + l31) * 8);
        oacc[dt] = __builtin_amdgcn_mfma_f32_32x32x16_bf16(vf, pb.v, oacc[dt], 0, 0, 0);
      }
    }

    __syncthreads();   // drains this chunk's prefetch; frees buffers
  }

  // epilogue: per-wave stride-33 transpose, write fp16 partial[slice]
  float* scratch = (float*)(smem + wq * 4352);
  u16* part = partial + (size_t)slice * NTOK * HID;
#pragma unroll
  for (int dt = 0; dt < 8; ++dt) {
#pragma unroll
    for (int r = 0; r < 16; ++r)
      scratch[TAU(r, lh) * 33 + l31] = oacc[dt][r];      // [d_local][q_local]
    u32 pk[8];
#pragma unroll
    for (int c2 = 0; c2 < 8; ++c2) {
      float f0 = scratch[(lh * 16 + 2 * c2) * 33 + l31];
      float f1 = scratch[(lh * 16 + 2 * c2 + 1) * 33 + l31];
      union { h16x2 h; u32 u; } cv;
      cv.h = __builtin_amdgcn_cvt_pkrtz(f0, f1);
      pk[c2] = cv.u;
    }
    u16* dst = part + (size_t)qrow * HID + dt * 32 + lh * 16;
    *reinterpret_cast<uint4*>(dst) = *reinterpret_cast<uint4*>(&pk[0]);
    *reinterpret_cast<uint4*>(dst + 8) = *reinterpret_cast<uint4*>(&pk[4]);
  }
}

// ---------------------------------------------------------------------------
// Reduce 8 fp16 slice-partials -> fp32 out
// ---------------------------------------------------------------------------
__global__ void reduce_kernel(const u16* __restrict__ partial, float* __restrict__ out) {
  size_t idx = (size_t)blockIdx.x * 256 + threadIdx.x;   // 262144 threads
  size_t base = idx * 8;
  float a[8] = {0.f, 0.f, 0.f, 0.f, 0.f, 0.f, 0.f, 0.f};
#pragma unroll
  for (int s = 0; s < NS; ++s) {
    uint4 v = *reinterpret_cast<const uint4*>(partial + (size_t)s * NTOK * HID + base);
    const __fp16* h = (const __fp16*)&v;
#pragma unroll
    for (int e = 0; e < 8; ++e) a[e] += (float)h[e];
  }
  *reinterpret_cast<float4*>(out + base) = make_float4(a[0], a[1], a[2], a[3]);
  *reinterpret_cast<float4*>(out + base + 4) = make_float4(a[4], a[5], a[6], a[7]);
}

extern "C" void kernel_launch(void* const* d_in, const int* in_sizes, int n_in,
                              void* d_out, int out_size, void* d_ws, size_t ws_size,
                              hipStream_t stream) {
  const float* query = (const float*)d_in[0];
  const float* key_  = (const float*)d_in[1];
  const float* value = (const float*)d_in[2];
  const float* Wq = (const float*)d_in[3];
  const float* bq = (const float*)d_in[4];
  const float* Wk = (const float*)d_in[5];
  const float* bk = (const float*)d_in[6];
  const float* Wv = (const float*)d_in[7];
  const float* bv = (const float*)d_in[8];
  float* out = (float*)d_out;

  unsigned char* ws = (unsigned char*)d_ws;
  u16* qws  = (u16*)(ws);                       // 4 MB  [8192][256] bf16
  u16* kws  = (u16*)(ws + (4u << 20));          // 4 MB  [8192][256] bf16
  u16* vtws = (u16*)(ws + (8u << 20));          // 4 MB  [256][8192] bf16
  u16* wcvt = (u16*)(ws + (12u << 20));         // 384 KB  3x[256][256] bf16
  u16* part = (u16*)(ws + (13u << 20));         // 32 MB  8x[8192][256] fp16

  wcvt_kernel<<<192, 256, 0, stream>>>(Wq, Wk, Wv, wcvt);
  proj_kernel<<<192, 256, 0, stream>>>(query, key_, value, wcvt, bq, bk, bv,
                                       qws, kws, vtws);
  attn_kernel<<<256, 512, 0, stream>>>(qws, kws, vtws, part);
  reduce_kernel<<<1024, 256, 0, stream>>>(part, out);
}